// Round 6
// baseline (230.310 us; speedup 1.0000x reference)
//
#include <hip/hip_runtime.h>
#include <hip/hip_fp16.h>
#include <math.h>

#define HH 512
#define WW 1024
#define NPIX (HH * WW)
#define KK 15
#define GAMMA 0.1f
#define MULTIPLIER 1.0f

// d_ws layout:
//   ws[0]            : float accumulator acc
//   ws[1]            : uint  done-counter
//   ws + 256 bytes   : uint2 pack[NPIX]  (8 B/pixel, 4 MB total -> fits per-XCD L2)
//     pack.x = half2(s, nx)   pack.y = half2(ny, nz)
// p_j is reconstructed as s_j * d_j where d_j is the ERP unit direction,
// a pure function of the pixel index (4 fast-trig ops).

__device__ inline unsigned int pack2f(float a, float b) {
  __half2 h = __floats2half2_rn(a, b);
  return *(unsigned int*)&h;
}
__device__ inline float2 up2(unsigned int u) {
  __half2 h = *(__half2*)&u;
  return __half22float2(h);
}

__device__ inline void erp_dir(int idx, float& dx, float& dy, float& dz) {
  int h = idx >> 10;          // idx / W (W=1024)
  int w = idx & (WW - 1);     // idx % W
  const float PI = 3.14159265358979323846f;
  float lat = (0.5f - (h + 0.5f) * (1.0f / HH)) * PI;
  float lon = ((w + 0.5f) * (1.0f / WW) - 0.5f) * (2.0f * PI);
  float sla = __sinf(lat), cla = __cosf(lat);
  float slo = __sinf(lon), clo = __cosf(lon);
  dx = cla * slo;
  dy = sla;
  dz = cla * clo;
}

__global__ __launch_bounds__(256) void prep_kernel(
    const float* __restrict__ sig1,
    const float* __restrict__ sig2,
    uint2* __restrict__ pack,
    float* __restrict__ acc,
    unsigned* __restrict__ done) {
  int i = blockIdx.x * 256 + threadIdx.x;
  if (i == 0) { acc[0] = 0.0f; done[0] = 0u; }

  float s  = sig1[i];
  float nx = sig2[i];
  float ny = sig2[NPIX + i];
  float nz = sig2[2 * NPIX + i];

  uint2 u;
  u.x = pack2f(s, nx);
  u.y = pack2f(ny, nz);
  pack[i] = u;
}

__global__ __launch_bounds__(256) void main_kernel(
    const uint2* __restrict__ pack,
    const float* __restrict__ weights,
    const int* __restrict__ nb,
    float* __restrict__ acc,
    unsigned* __restrict__ done,
    float* __restrict__ out) {
  int i = blockIdx.x * 256 + threadIdx.x;   // grid covers NPIX exactly

  // center: direction from trig, (s, n) from table (coalesced, also warms L2)
  float dix, diy, diz;
  erp_dir(i, dix, diy, diz);
  uint2 c = pack[i];
  float2 c0 = up2(c.x), c1 = up2(c.y);
  float si = c0.x, nix = c0.y, niy = c1.x, niz = c1.y;
  float pn = si * (dix * nix + diy * niy + diz * niz);

  // neighbour indices (non-temporal: don't evict the gather table from L2)
  int j[KK];
#pragma unroll
  for (int k = 0; k < KK; ++k) j[k] = __builtin_nontemporal_load(&nb[k * NPIX + i]);

  // gathers: 8 B each from the L2-resident 4 MB table
  uint2 g[KK];
#pragma unroll
  for (int k = 0; k < KK; ++k) g[k] = pack[j[k]];

  float wv[KK];
#pragma unroll
  for (int k = 0; k < KK; ++k) wv[k] = __builtin_nontemporal_load(&weights[k * NPIX + i]);

  float sq = 0.0f, t2 = 0.0f;
#pragma unroll
  for (int k = 0; k < KK; ++k) {
    float djx, djy, djz;
    erp_dir(j[k], djx, djy, djz);
    float2 g0 = up2(g[k].x), g1 = up2(g[k].y);
    float sj = g0.x, njx = g0.y, njy = g1.x, njz = g1.y;
    // aux1 = pn_i - p_j . n_i = pn_i - s_j * (d_j . n_i)
    float aux1 = pn - sj * (djx * nix + djy * niy + djz * niz);
    float ddx = nix - njx, ddy = niy - njy, ddz = niz - njz;
    float aux2 = sqrtf(ddx * ddx + ddy * ddy + ddz * ddz);
    float aw = aux1 * wv[k];
    sq += aw * aw;
    t2 += aux2 * wv[k];
  }
  float local = sqrtf(sq) + GAMMA * t2;

  // wave (64-lane) reduction
  for (int off = 32; off > 0; off >>= 1)
    local += __shfl_down(local, off, 64);

  __shared__ float smem[4];
  int lane = threadIdx.x & 63;
  int wid = threadIdx.x >> 6;
  if (lane == 0) smem[wid] = local;
  __syncthreads();
  if (threadIdx.x == 0) {
    float s = smem[0] + smem[1] + smem[2] + smem[3];
    atomicAdd(acc, s);
    __threadfence();
    unsigned t = atomicAdd(done, 1u);
    if (t == gridDim.x - 1) {            // last block finalizes (saves a launch)
      __threadfence();
      float a = *((volatile float*)acc);
      out[0] = MULTIPLIER * a * (1.0f / (float)NPIX);
    }
  }
}

extern "C" void kernel_launch(void* const* d_in, const int* in_sizes, int n_in,
                              void* d_out, int out_size, void* d_ws, size_t ws_size,
                              hipStream_t stream) {
  const float* sig1 = (const float*)d_in[0];
  const float* sig2 = (const float*)d_in[1];
  const float* wts  = (const float*)d_in[2];
  const int*   nb   = (const int*)d_in[3];
  float* out = (float*)d_out;

  float*    acc  = (float*)d_ws;
  unsigned* done = (unsigned*)d_ws + 1;
  uint2*    pack = (uint2*)((char*)d_ws + 256);

  int blocks = NPIX / 256;  // 2048
  hipLaunchKernelGGL(prep_kernel, dim3(blocks), dim3(256), 0, stream, sig1, sig2, pack, acc, done);
  hipLaunchKernelGGL(main_kernel, dim3(blocks), dim3(256), 0, stream, pack, wts, nb, acc, done, out);
}

// Round 7
// 211.732 us; speedup vs baseline: 1.0877x; 1.0877x over previous
//
#include <hip/hip_runtime.h>
#include <hip/hip_fp16.h>
#include <math.h>

#define HH 512
#define WW 1024
#define NPIX (HH * WW)
#define KK 15
#define GAMMA 0.1f
#define MULTIPLIER 1.0f

typedef unsigned int u32x2 __attribute__((ext_vector_type(2)));

// d_ws layout:
//   ws[0]          : float accumulator acc
//   ws[1]          : uint done-counter
//   ws + 256 bytes : u32x2 pack[NPIX] (8 B/pixel, 4 MB -> L2-resident)
//     pack.x = half2(s, nx)   pack.y = half2(ny, nz)

__device__ inline unsigned int pack2f(float a, float b) {
  __half2 h = __floats2half2_rn(a, b);
  return *(unsigned int*)&h;
}
__device__ inline float2 up2(unsigned int u) {
  __half2 h = *(__half2*)&u;
  return __half22float2(h);
}

__device__ inline void erp_dir(int idx, float& dx, float& dy, float& dz) {
  int h = idx >> 10;          // idx / W (W=1024)
  int w = idx & (WW - 1);     // idx % W
  const float PI = 3.14159265358979323846f;
  float lat = (0.5f - (h + 0.5f) * (1.0f / HH)) * PI;
  float lon = ((w + 0.5f) * (1.0f / WW) - 0.5f) * (2.0f * PI);
  float sla = __sinf(lat), cla = __cosf(lat);
  float slo = __sinf(lon), clo = __cosf(lon);
  dx = cla * slo;
  dy = sla;
  dz = cla * clo;
}

__global__ __launch_bounds__(256) void prep_kernel(
    const float* __restrict__ sig1,
    const float* __restrict__ sig2,
    u32x2* __restrict__ pack,
    float* __restrict__ acc,
    unsigned* __restrict__ done) {
  int i = blockIdx.x * 256 + threadIdx.x;
  if (i == 0) { acc[0] = 0.0f; done[0] = 0u; }

  float s  = sig1[i];
  float nx = sig2[i];
  float ny = sig2[NPIX + i];
  float nz = sig2[2 * NPIX + i];

  u32x2 u;
  u.x = pack2f(s, nx);
  u.y = pack2f(ny, nz);
  pack[i] = u;
}

__global__ __launch_bounds__(256) void main_kernel(
    const u32x2* __restrict__ pack,
    const float* __restrict__ weights,
    const int* __restrict__ nb,
    float* __restrict__ acc,
    unsigned* __restrict__ done,
    float* __restrict__ out) {
  int i = blockIdx.x * 256 + threadIdx.x;   // grid covers NPIX exactly

  // ---- all compiler-tracked loads first (their auto-waitcnts stay valid) ----
  int j[KK];
#pragma unroll
  for (int k = 0; k < KK; ++k) j[k] = nb[k * NPIX + i];

  u32x2 c = pack[i];

  float wv[KK];
#pragma unroll
  for (int k = 0; k < KK; ++k) wv[k] = weights[k * NPIX + i];

  // center quantities (waits only on c per compiler's own counting)
  float dix, diy, diz;
  erp_dir(i, dix, diy, diz);
  float2 c0 = up2(c.x), c1 = up2(c.y);
  float si = c0.x, nix = c0.y, niy = c1.x, niz = c1.y;
  float pn = si * (dix * nix + diy * niy + diz * niz);

  // ---- forced-MLP gathers: 15 asm loads, all outstanding simultaneously ----
  u32x2 g[KK];
#pragma unroll
  for (int k = 0; k < KK; ++k) {
    unsigned off = (unsigned)j[k] * 8u;   // byte offset into 4 MB table
    asm volatile("global_load_dwordx2 %0, %1, %2"
                 : "=v"(g[k])
                 : "v"(off), "s"(pack));
  }
  asm volatile("s_waitcnt vmcnt(0)" ::: "memory");
  __builtin_amdgcn_sched_barrier(0);   // nothing hoists above the drain

  // ---- consume: per-k independent -> ILP hides trig latency ----
  float sq = 0.0f, t2 = 0.0f;
#pragma unroll
  for (int k = 0; k < KK; ++k) {
    float djx, djy, djz;
    erp_dir(j[k], djx, djy, djz);
    float2 g0 = up2(g[k].x), g1 = up2(g[k].y);
    float sj = g0.x, njx = g0.y, njy = g1.x, njz = g1.y;
    float aux1 = pn - sj * (djx * nix + djy * niy + djz * niz);
    float ddx = nix - njx, ddy = niy - njy, ddz = niz - njz;
    float aux2 = sqrtf(ddx * ddx + ddy * ddy + ddz * ddz);
    float aw = aux1 * wv[k];
    sq += aw * aw;
    t2 += aux2 * wv[k];
  }
  float local = sqrtf(sq) + GAMMA * t2;

  // wave (64-lane) reduction
  for (int off = 32; off > 0; off >>= 1)
    local += __shfl_down(local, off, 64);

  __shared__ float smem[4];
  int lane = threadIdx.x & 63;
  int wid = threadIdx.x >> 6;
  if (lane == 0) smem[wid] = local;
  __syncthreads();
  if (threadIdx.x == 0) {
    float s = smem[0] + smem[1] + smem[2] + smem[3];
    atomicAdd(acc, s);
    __threadfence();
    unsigned t = atomicAdd(done, 1u);
    if (t == gridDim.x - 1) {            // last block finalizes (saves a launch)
      __threadfence();
      float a = *((volatile float*)acc);
      out[0] = MULTIPLIER * a * (1.0f / (float)NPIX);
    }
  }
}

extern "C" void kernel_launch(void* const* d_in, const int* in_sizes, int n_in,
                              void* d_out, int out_size, void* d_ws, size_t ws_size,
                              hipStream_t stream) {
  const float* sig1 = (const float*)d_in[0];
  const float* sig2 = (const float*)d_in[1];
  const float* wts  = (const float*)d_in[2];
  const int*   nb   = (const int*)d_in[3];
  float* out = (float*)d_out;

  float*    acc  = (float*)d_ws;
  unsigned* done = (unsigned*)d_ws + 1;
  u32x2*    pack = (u32x2*)((char*)d_ws + 256);

  int blocks = NPIX / 256;  // 2048
  hipLaunchKernelGGL(prep_kernel, dim3(blocks), dim3(256), 0, stream, sig1, sig2, pack, acc, done);
  hipLaunchKernelGGL(main_kernel, dim3(blocks), dim3(256), 0, stream, pack, wts, nb, acc, done, out);
}